// Round 15
// baseline (84.310 us; speedup 1.0000x reference)
//
#include <hip/hip_runtime.h>

namespace {
constexpr int N_ = 8, C_ = 32, H_ = 256, W_ = 512, DISP_ = 25;
constexpr int CH = H_ * W_;   // elements between channels / disparities
constexpr int TILE = 256;     // output columns per block
constexpr int NSS = C_ / 4;   // 8 supersteps, 4 channels = 2 packed pairs
constexpr int YST = 288;      // staged y cols per pair: [tb-12, tb+276)
constexpr int BUFU = 2 * YST; // u32 per LDS buffer (576)
}

typedef __attribute__((ext_vector_type(2))) _Float16 h2;

static __device__ __forceinline__ h2 u2h(unsigned u) {
  return __builtin_bit_cast(h2, u);
}
static __device__ __forceinline__ unsigned pk(float a, float b) {
  return __builtin_bit_cast(unsigned, __builtin_amdgcn_cvt_pkrtz(a, b));
}

// r15: x-in-registers (no LDS round trip) + 4-channel supersteps (8 phases).
// r14 post-mortem: 3 structures all land ~81 us with nothing saturated ->
// per-phase exposed latency chain x 16 phases is the attractor. Halve the
// phase count (4ch supersteps) and shorten the chain (x loads go straight
// to regs; raw s_barrier with lgkmcnt-only drain keeps x loads in flight
// across the barrier).
//
// 256 threads/block = 256-col tile of one (n,h) row; grid = N*H*2.
//   tl = tid & 63 -> 4 output cols (w0l = 4*tl); g = tid>>6 -> disparity group
//   G0: i in [0,7) OFF +4 | G1: [7,13) OFF 0 | G2: [13,19) OFF -8
//   G3: [19,25) OFF -12;  LDS window idx m = cw + 12 - OFF - i in [0,12)
// y LDS buffer: 2 pairs x 288 cols of f16x2 (channels 4s+2p, 4s+2p+1 packed).
// Staging: thread handles u32 slots j = {tid, tid+256, tid+512 (tid<64)};
// p = j/288, jc = j%288, global col clamp(tb-12+jc) (clamped cols only feed
// epilogue-zeroed outputs). Math: d = pk_sub_f16(x2,y2); a = d & 0x7FFF7FFF;
// acc = v_dot2_f32_f16(a, 1, acc)  (f32 accum; r14 measured absmax 0.5).
// Registers: acc 28 + xl 16 + xpk 8 + ystage 6 + yw 12 + addr ~20 ~= 90;
// launch_bounds(256,4) cap 128, margin ~38 (WRITE_SIZE = spill tripwire).
template <int G>
__device__ __forceinline__ void body(const float* xb, const float* yj0,
                                     const float* yj1, const float* yj2,
                                     bool e2, int wj0, int wj1, int wj2,
                                     float* __restrict__ op, unsigned* lds,
                                     int w0l, int w0g) {
  constexpr int I0 = (G == 0) ? 0 : (G == 1) ? 7 : (G == 2) ? 13 : 19;
  constexpr int NI = (G == 0) ? 7 : 6;
  constexpr int OFF = (G == 0) ? 4 : (G == 1) ? 0 : (G == 2) ? -8 : -12;
  const int jb = w0l + (OFF + 12);  // 16B-aligned window base (u32 units)
  const h2 one = {(_Float16)1.0f, (_Float16)1.0f};

  float acc[NI][4];
#pragma unroll
  for (int il = 0; il < NI; ++il)
#pragma unroll
    for (int cw = 0; cw < 4; ++cw) acc[il][cw] = 0.0f;

  float4 xl0, xl1, xl2, xl3;
  float ya0, ya1, yb0, yb1, yc0, yc1;

#define YLOAD(s)                                                          \
  do {                                                                    \
    const float* b0 = yj0 + (size_t)(s) * 4 * CH;                         \
    ya0 = b0[0]; ya1 = b0[CH];                                            \
    const float* b1 = yj1 + (size_t)(s) * 4 * CH;                         \
    yb0 = b1[0]; yb1 = b1[CH];                                            \
    if (e2) {                                                             \
      const float* b2 = yj2 + (size_t)(s) * 4 * CH;                       \
      yc0 = b2[0]; yc1 = b2[CH];                                          \
    }                                                                     \
  } while (0)

#define YWRITE(buf)                                                       \
  do {                                                                    \
    unsigned* wp = lds + (buf)*BUFU;                                      \
    wp[wj0] = pk(ya0, ya1);                                               \
    wp[wj1] = pk(yb0, yb1);                                               \
    if (e2) wp[wj2] = pk(yc0, yc1);                                       \
  } while (0)

#define XLOAD(s)                                                          \
  do {                                                                    \
    const float* xc = xb + (size_t)(s) * 4 * CH;                          \
    xl0 = *reinterpret_cast<const float4*>(xc);                           \
    xl1 = *reinterpret_cast<const float4*>(xc + CH);                      \
    xl2 = *reinterpret_cast<const float4*>(xc + 2 * CH);                  \
    xl3 = *reinterpret_cast<const float4*>(xc + 3 * CH);                  \
  } while (0)

#define COMPUTE(buf)                                                      \
  do {                                                                    \
    const unsigned xpk0[4] = {pk(xl0.x, xl1.x), pk(xl0.y, xl1.y),         \
                              pk(xl0.z, xl1.z), pk(xl0.w, xl1.w)};        \
    const unsigned xpk1[4] = {pk(xl2.x, xl3.x), pk(xl2.y, xl3.y),         \
                              pk(xl2.z, xl3.z), pk(xl2.w, xl3.w)};        \
    const unsigned* bp = lds + (buf)*BUFU;                                \
    _Pragma("unroll") for (int p = 0; p < 2; ++p) {                       \
      const unsigned* yp = bp + p * YST + jb;                             \
      const uint4 q0 = *reinterpret_cast<const uint4*>(yp);               \
      const uint4 q1 = *reinterpret_cast<const uint4*>(yp + 4);           \
      const uint4 q2 = *reinterpret_cast<const uint4*>(yp + 8);           \
      const unsigned yw[12] = {q0.x, q0.y, q0.z, q0.w, q1.x, q1.y,        \
                               q1.z, q1.w, q2.x, q2.y, q2.z, q2.w};       \
      const unsigned* xq = p ? xpk1 : xpk0;                               \
      _Pragma("unroll") for (int il = 0; il < NI; ++il) {                 \
        _Pragma("unroll") for (int cw = 0; cw < 4; ++cw) {                \
          h2 d = u2h(xq[cw]) - u2h(yw[cw + 12 - OFF - (I0 + il)]);        \
          h2 a = u2h(__builtin_bit_cast(unsigned, d) & 0x7FFF7FFFu);      \
          acc[il][cw] = __builtin_amdgcn_fdot2(a, one, acc[il][cw], false);\
        }                                                                 \
      }                                                                   \
    }                                                                     \
  } while (0)

  // Prologue: stage superstep 0 (y via LDS, x in regs).
  YLOAD(0);
  XLOAD(0);
  YWRITE(0);
  asm volatile("s_waitcnt lgkmcnt(0)" ::: "memory");
  __builtin_amdgcn_s_barrier();

#pragma unroll 1
  for (int s = 0; s < NSS; ++s) {
    if (s + 1 < NSS) YLOAD(s + 1);  // y loads: full compute phase of slack
    COMPUTE(s & 1);                 // consumes xl (cvt at top), frees them
    if (s + 1 < NSS) {
      XLOAD(s + 1);                 // stays in flight across the barrier
      YWRITE((s + 1) & 1);          // waits on YLOAD(s+1)
    }
    asm volatile("s_waitcnt lgkmcnt(0)" ::: "memory");  // ds writes visible
    __builtin_amdgcn_s_barrier();   // no vmcnt drain: x loads keep flying
  }

#undef YLOAD
#undef YWRITE
#undef XLOAD
#undef COMPUTE

  // Epilogue: zero out-of-overlap (w,i) pairs, coalesced float4 stores.
#pragma unroll
  for (int il = 0; il < NI; ++il) {
    const int i = I0 + il;
    const int j0 = w0g - i + 12;  // y column used by cw=0
    float4 v;
    v.x = ((unsigned)(j0 + 0) < (unsigned)W_) ? acc[il][0] : 0.0f;
    v.y = ((unsigned)(j0 + 1) < (unsigned)W_) ? acc[il][1] : 0.0f;
    v.z = ((unsigned)(j0 + 2) < (unsigned)W_) ? acc[il][2] : 0.0f;
    v.w = ((unsigned)(j0 + 3) < (unsigned)W_) ? acc[il][3] : 0.0f;
    *reinterpret_cast<float4*>(op + (size_t)i * CH) = v;
  }
}

__global__ __launch_bounds__(256, 4) void rescost_kernel(
    const float* __restrict__ x, const float* __restrict__ y,
    float* __restrict__ out) {
  __shared__ __align__(16) unsigned lds[2 * BUFU];  // 4608 B

  const int tid = threadIdx.x;
  const int tl = tid & 63;   // column group within tile
  const int g = tid >> 6;    // disparity group (wave-uniform)
  const int bid = blockIdx.x;
  const int tile = bid & 1;  // which 256-col half of the row
  const int r = bid >> 1;    // row in [0, N*H)
  const int n = r >> 8;      // H = 256
  const int h = r & (H_ - 1);
  const int tb = tile * TILE;
  const int w0l = tl << 2;
  const int w0g = tb + w0l;

  const size_t row_base = ((size_t)n * C_ * H_ + (size_t)h) * W_;

  // Staging slots j = {tid, tid+256, tid+512 (tid<64 only; wave-uniform)}.
  // p = j/288 selects the packed channel pair, jc = j%288 the staged column.
  const int p1 = (tid >= 32) ? 1 : 0;
  const int jc0 = tid;
  const int jc1 = tid + 256 - p1 * YST;
  const int jc2 = tid + 512 - YST;  // p = 1
  const bool e2 = (tid < 64);

  auto yclamp = [&](int jc) {
    int c = tb - 12 + jc;
    c = c < 0 ? 0 : (c > W_ - 1 ? W_ - 1 : c);
    return c;
  };
  const float* yj0 = y + row_base + yclamp(jc0);                 // pair 0
  const float* yj1 = y + row_base + yclamp(jc1) + p1 * 2 * CH;   // pair p1
  const float* yj2 = y + row_base + yclamp(jc2) + 2 * CH;        // pair 1
  const int wj0 = tid, wj1 = tid + 256, wj2 = tid + 512;

  const float* xb = x + row_base + w0g;
  float* op = out + (size_t)n * DISP_ * CH + (size_t)h * W_ + w0g;

  if (g == 0)
    body<0>(xb, yj0, yj1, yj2, e2, wj0, wj1, wj2, op, lds, w0l, w0g);
  else if (g == 1)
    body<1>(xb, yj0, yj1, yj2, e2, wj0, wj1, wj2, op, lds, w0l, w0g);
  else if (g == 2)
    body<2>(xb, yj0, yj1, yj2, e2, wj0, wj1, wj2, op, lds, w0l, w0g);
  else
    body<3>(xb, yj0, yj1, yj2, e2, wj0, wj1, wj2, op, lds, w0l, w0g);
}

extern "C" void kernel_launch(void* const* d_in, const int* in_sizes, int n_in,
                              void* d_out, int out_size, void* d_ws, size_t ws_size,
                              hipStream_t stream) {
  const float* x = (const float*)d_in[0];
  const float* y = (const float*)d_in[1];
  float* out = (float*)d_out;
  dim3 grid(N_ * H_ * 2);  // 256-col tile per block
  dim3 block(256);
  hipLaunchKernelGGL(rescost_kernel, grid, block, 0, stream, x, y, out);
}

// Round 17
// 67.162 us; speedup vs baseline: 1.2553x; 1.2553x over previous
//
#include <hip/hip_runtime.h>

namespace {
constexpr int N_ = 8, C_ = 32, H_ = 256, W_ = 512, DISP_ = 25;
constexpr int CH = H_ * W_;   // elements between channels / disparities
constexpr int TILE = 256;     // output columns per block
constexpr int NSS = C_ / 2;   // 16 supersteps, 2 channels packed per step
constexpr int YST = 288;      // staged y cols: [tb-12, tb+276)
constexpr int YOFF = 256;     // y region start (u32 units) inside a buffer
constexpr int BUF = 560;      // u32 stride per buffer
}

typedef __attribute__((ext_vector_type(2))) _Float16 h2;
typedef __attribute__((ext_vector_type(4))) float f4;  // native vector for nt-store

__device__ __forceinline__ h2 u2h(unsigned u) { return __builtin_bit_cast(h2, u); }
__device__ __forceinline__ unsigned h2u(h2 v) { return __builtin_bit_cast(unsigned, v); }

// r17 = r14 (packed-f16 channel pairs, tied-best 81.3 us) + NON-TEMPORAL
// output stores (via clang-native f4; HIP float4 class is rejected by the
// builtin — r16 compile fail). 8-structure post-mortem: dur invariant
// (81-84 us) to occupancy (23-71%), VALU (32-52%), phase count, staging
// style -> binding resource is L3/HBM traffic shared by all structures.
// Inputs (256 MB) ~fit Infinity Cache; the 102 MB output streaming through
// L3 evicts them (steady 139 MB re-fetch/iter). nt stores (evict-first)
// keep inputs resident: predict FETCH < 60 MB and dur 55-70 us; if
// unchanged, the traffic theory is falsified.
template <int G>
__device__ __forceinline__ void body(const float* px, const float* py0,
                                     const float* py1, bool extra,
                                     float* __restrict__ op, unsigned* lds,
                                     int tid, int w0l, int w0g) {
  constexpr int I0 = (G == 0) ? 0 : (G == 1) ? 7 : (G == 2) ? 13 : 19;
  constexpr int NI = (G == 0) ? 7 : 6;
  constexpr int OFF = (G == 0) ? 4 : (G == 1) ? 0 : (G == 2) ? -8 : -12;

  const h2 one = {(_Float16)1.0f, (_Float16)1.0f};

  float acc[NI][4];
#pragma unroll
  for (int il = 0; il < NI; ++il)
#pragma unroll
    for (int cw = 0; cw < 4; ++cw) acc[il][cw] = 0.0f;

  float a0, a1, b0, b1, c0, c1;

#define SLOAD()                                                           \
  do {                                                                    \
    a0 = px[0]; a1 = px[CH];                                              \
    b0 = py0[0]; b1 = py0[CH];                                            \
    if (extra) { c0 = py1[0]; c1 = py1[CH]; }                             \
    px += 2 * CH; py0 += 2 * CH; py1 += 2 * CH;                           \
  } while (0)

#define SWRITE(bsel)                                                      \
  do {                                                                    \
    unsigned* wp = lds + (bsel)*BUF;                                      \
    h2 pa = __builtin_bit_cast(h2, __builtin_amdgcn_cvt_pkrtz(a0, a1));   \
    h2 pb = __builtin_bit_cast(h2, __builtin_amdgcn_cvt_pkrtz(b0, b1));   \
    wp[tid] = h2u(pa);                                                    \
    wp[YOFF + tid] = h2u(pb);                                             \
    if (extra) {                                                          \
      h2 pc = __builtin_bit_cast(h2, __builtin_amdgcn_cvt_pkrtz(c0, c1)); \
      wp[YOFF + 256 + tid] = h2u(pc);                                     \
    }                                                                     \
  } while (0)

#define COMPUTE(bsel)                                                     \
  do {                                                                    \
    const unsigned* bp = lds + (bsel)*BUF;                                \
    const uint4 xq = *reinterpret_cast<const uint4*>(bp + w0l);           \
    const uint4 q0 = *reinterpret_cast<const uint4*>(bp + YOFF + w0l +    \
                                                     (OFF + 12));         \
    const uint4 q1 = *reinterpret_cast<const uint4*>(bp + YOFF + w0l +    \
                                                     (OFF + 12) + 4);    \
    const uint4 q2 = *reinterpret_cast<const uint4*>(bp + YOFF + w0l +    \
                                                     (OFF + 12) + 8);    \
    const unsigned xs[4] = {xq.x, xq.y, xq.z, xq.w};                      \
    const unsigned yw[12] = {q0.x, q0.y, q0.z, q0.w, q1.x, q1.y, q1.z,    \
                             q1.w, q2.x, q2.y, q2.z, q2.w};               \
    _Pragma("unroll") for (int il = 0; il < NI; ++il) {                   \
      _Pragma("unroll") for (int cw = 0; cw < 4; ++cw) {                  \
        h2 d = u2h(xs[cw]) - u2h(yw[cw + 12 - (I0 + il) - OFF]);          \
        h2 a = u2h(h2u(d) & 0x7FFF7FFFu);                                 \
        acc[il][cw] = __builtin_amdgcn_fdot2(a, one, acc[il][cw], false); \
      }                                                                   \
    }                                                                     \
  } while (0)

  // Prologue: stage superstep 0 into buffer 0.
  SLOAD();
  SWRITE(0);
  __syncthreads();

  int cb = 0;
#pragma unroll 1
  for (int s = 0; s < NSS; ++s) {
    const bool more = (s + 1 < NSS);
    if (more) SLOAD();   // issue next superstep's global loads early
    COMPUTE(cb);         // compute hides the load latency
    if (more) SWRITE(cb ^ 1);
    __syncthreads();     // writes visible; buffer reuse ordered
    cb ^= 1;
  }

#undef SLOAD
#undef SWRITE
#undef COMPUTE

  // Epilogue: zero out-of-overlap (w,i) pairs; NON-TEMPORAL stores (output
  // is write-once/never-read -> evict-first keeps inputs L3-resident).
#pragma unroll
  for (int il = 0; il < NI; ++il) {
    const int i = I0 + il;
    const int j0 = w0g - i + 12;  // y column used by cw=0
    f4 v;
    v.x = ((unsigned)(j0 + 0) < (unsigned)W_) ? acc[il][0] : 0.0f;
    v.y = ((unsigned)(j0 + 1) < (unsigned)W_) ? acc[il][1] : 0.0f;
    v.z = ((unsigned)(j0 + 2) < (unsigned)W_) ? acc[il][2] : 0.0f;
    v.w = ((unsigned)(j0 + 3) < (unsigned)W_) ? acc[il][3] : 0.0f;
    __builtin_nontemporal_store(v, reinterpret_cast<f4*>(op + (size_t)i * CH));
  }
}

__global__ __launch_bounds__(256, 5) void rescost_kernel(
    const float* __restrict__ x, const float* __restrict__ y,
    float* __restrict__ out) {
  __shared__ __align__(16) unsigned lds[2 * BUF];  // 4480 B

  const int tid = threadIdx.x;
  const int tl = tid & 63;   // column group within tile
  const int g = tid >> 6;    // disparity group (wave-uniform)
  const int bid = blockIdx.x;
  const int tile = bid & 1;  // which 256-col half of the row
  const int r = bid >> 1;    // row in [0, N*H)
  const int n = r >> 8;      // H = 256
  const int h = r & (H_ - 1);
  const int tb = tile * TILE;
  const int w0l = tl << 2;
  const int w0g = tb + w0l;

  const size_t row_base = ((size_t)n * C_ * H_ + (size_t)h) * W_;

  // Staging columns (clamped at image edges; clamped values only reach
  // disparity outputs the epilogue zeroes).
  const int gx = tb + tid;
  int gy0 = tb - 12 + tid;
  gy0 = gy0 < 0 ? 0 : (gy0 > W_ - 1 ? W_ - 1 : gy0);
  int gy1 = tb - 12 + 256 + tid;
  gy1 = gy1 < 0 ? 0 : (gy1 > W_ - 1 ? W_ - 1 : gy1);
  const bool extra = tid < (YST - 256);  // 32 threads stage the y tail

  const float* px = x + row_base + gx;
  const float* py0 = y + row_base + gy0;
  const float* py1 = y + row_base + gy1;
  float* op = out + (size_t)n * DISP_ * CH + (size_t)h * W_ + w0g;

  if (g == 0)
    body<0>(px, py0, py1, extra, op, lds, tid, w0l, w0g);
  else if (g == 1)
    body<1>(px, py0, py1, extra, op, lds, tid, w0l, w0g);
  else if (g == 2)
    body<2>(px, py0, py1, extra, op, lds, tid, w0l, w0g);
  else
    body<3>(px, py0, py1, extra, op, lds, tid, w0l, w0g);
}

extern "C" void kernel_launch(void* const* d_in, const int* in_sizes, int n_in,
                              void* d_out, int out_size, void* d_ws, size_t ws_size,
                              hipStream_t stream) {
  const float* x = (const float*)d_in[0];
  const float* y = (const float*)d_in[1];
  float* out = (float*)d_out;
  dim3 grid(N_ * H_ * 2);  // 256-col tile per block
  dim3 block(256);
  hipLaunchKernelGGL(rescost_kernel, grid, block, 0, stream, x, y, out);
}

// Round 18
// 66.213 us; speedup vs baseline: 1.2733x; 1.0143x over previous
//
#include <hip/hip_runtime.h>

namespace {
constexpr int N_ = 8, C_ = 32, H_ = 256, W_ = 512, DISP_ = 25;
constexpr int CH = H_ * W_;   // elements between channels / disparities
constexpr int TILE = 256;     // output columns per block
constexpr int NSS = C_ / 2;   // 16 supersteps, 2 channels packed per step
constexpr int YST = 288;      // staged y cols: [tb-12, tb+276)
constexpr int YOFF = 256;     // y region start (u32 units) inside a buffer
constexpr int BUF = 560;      // u32 stride per buffer
}

typedef __attribute__((ext_vector_type(2))) _Float16 h2;
typedef __attribute__((ext_vector_type(4))) float f4;  // native vector for nt-store

__device__ __forceinline__ h2 u2h(unsigned u) { return __builtin_bit_cast(h2, u); }
__device__ __forceinline__ unsigned h2u(h2 v) { return __builtin_bit_cast(unsigned, v); }

// r18 = r17 (packed-f16 pairs + nt-stores, 67.2 us) with ONE change:
// __launch_bounds__(256,8) (was 5). r17 post-mortem: nt-stores broke the 81us
// attractor by taking the output out of the L3/L2 write-allocate path; now at
// 241 MB / 67 us = 3.6 TB/s = 57% of achievable, occ 74% (~6 waves/SIMD),
// nothing else saturated -> remaining lever is memory-level parallelism.
// Forcing 8 waves/SIMD (cap 64 regs; measured usage ~60-65) is a deliberate
// margin-rule violation with WRITE_SIZE as the spill tripwire; fallback r17.
template <int G>
__device__ __forceinline__ void body(const float* px, const float* py0,
                                     const float* py1, bool extra,
                                     float* __restrict__ op, unsigned* lds,
                                     int tid, int w0l, int w0g) {
  constexpr int I0 = (G == 0) ? 0 : (G == 1) ? 7 : (G == 2) ? 13 : 19;
  constexpr int NI = (G == 0) ? 7 : 6;
  constexpr int OFF = (G == 0) ? 4 : (G == 1) ? 0 : (G == 2) ? -8 : -12;

  const h2 one = {(_Float16)1.0f, (_Float16)1.0f};

  float acc[NI][4];
#pragma unroll
  for (int il = 0; il < NI; ++il)
#pragma unroll
    for (int cw = 0; cw < 4; ++cw) acc[il][cw] = 0.0f;

  float a0, a1, b0, b1, c0, c1;

#define SLOAD()                                                           \
  do {                                                                    \
    a0 = px[0]; a1 = px[CH];                                              \
    b0 = py0[0]; b1 = py0[CH];                                            \
    if (extra) { c0 = py1[0]; c1 = py1[CH]; }                             \
    px += 2 * CH; py0 += 2 * CH; py1 += 2 * CH;                           \
  } while (0)

#define SWRITE(bsel)                                                      \
  do {                                                                    \
    unsigned* wp = lds + (bsel)*BUF;                                      \
    h2 pa = __builtin_bit_cast(h2, __builtin_amdgcn_cvt_pkrtz(a0, a1));   \
    h2 pb = __builtin_bit_cast(h2, __builtin_amdgcn_cvt_pkrtz(b0, b1));   \
    wp[tid] = h2u(pa);                                                    \
    wp[YOFF + tid] = h2u(pb);                                             \
    if (extra) {                                                          \
      h2 pc = __builtin_bit_cast(h2, __builtin_amdgcn_cvt_pkrtz(c0, c1)); \
      wp[YOFF + 256 + tid] = h2u(pc);                                     \
    }                                                                     \
  } while (0)

#define COMPUTE(bsel)                                                     \
  do {                                                                    \
    const unsigned* bp = lds + (bsel)*BUF;                                \
    const uint4 xq = *reinterpret_cast<const uint4*>(bp + w0l);           \
    const uint4 q0 = *reinterpret_cast<const uint4*>(bp + YOFF + w0l +    \
                                                     (OFF + 12));         \
    const uint4 q1 = *reinterpret_cast<const uint4*>(bp + YOFF + w0l +    \
                                                     (OFF + 12) + 4);    \
    const uint4 q2 = *reinterpret_cast<const uint4*>(bp + YOFF + w0l +    \
                                                     (OFF + 12) + 8);    \
    const unsigned xs[4] = {xq.x, xq.y, xq.z, xq.w};                      \
    const unsigned yw[12] = {q0.x, q0.y, q0.z, q0.w, q1.x, q1.y, q1.z,    \
                             q1.w, q2.x, q2.y, q2.z, q2.w};               \
    _Pragma("unroll") for (int il = 0; il < NI; ++il) {                   \
      _Pragma("unroll") for (int cw = 0; cw < 4; ++cw) {                  \
        h2 d = u2h(xs[cw]) - u2h(yw[cw + 12 - (I0 + il) - OFF]);          \
        h2 a = u2h(h2u(d) & 0x7FFF7FFFu);                                 \
        acc[il][cw] = __builtin_amdgcn_fdot2(a, one, acc[il][cw], false); \
      }                                                                   \
    }                                                                     \
  } while (0)

  // Prologue: stage superstep 0 into buffer 0.
  SLOAD();
  SWRITE(0);
  __syncthreads();

  int cb = 0;
#pragma unroll 1
  for (int s = 0; s < NSS; ++s) {
    const bool more = (s + 1 < NSS);
    if (more) SLOAD();   // issue next superstep's global loads early
    COMPUTE(cb);         // compute hides the load latency
    if (more) SWRITE(cb ^ 1);
    __syncthreads();     // writes visible; buffer reuse ordered
    cb ^= 1;
  }

#undef SLOAD
#undef SWRITE
#undef COMPUTE

  // Epilogue: zero out-of-overlap (w,i) pairs; NON-TEMPORAL stores (output
  // is write-once/never-read -> evict-first keeps it out of L2/L3).
#pragma unroll
  for (int il = 0; il < NI; ++il) {
    const int i = I0 + il;
    const int j0 = w0g - i + 12;  // y column used by cw=0
    f4 v;
    v.x = ((unsigned)(j0 + 0) < (unsigned)W_) ? acc[il][0] : 0.0f;
    v.y = ((unsigned)(j0 + 1) < (unsigned)W_) ? acc[il][1] : 0.0f;
    v.z = ((unsigned)(j0 + 2) < (unsigned)W_) ? acc[il][2] : 0.0f;
    v.w = ((unsigned)(j0 + 3) < (unsigned)W_) ? acc[il][3] : 0.0f;
    __builtin_nontemporal_store(v, reinterpret_cast<f4*>(op + (size_t)i * CH));
  }
}

__global__ __launch_bounds__(256, 8) void rescost_kernel(
    const float* __restrict__ x, const float* __restrict__ y,
    float* __restrict__ out) {
  __shared__ __align__(16) unsigned lds[2 * BUF];  // 4480 B

  const int tid = threadIdx.x;
  const int tl = tid & 63;   // column group within tile
  const int g = tid >> 6;    // disparity group (wave-uniform)
  const int bid = blockIdx.x;
  const int tile = bid & 1;  // which 256-col half of the row
  const int r = bid >> 1;    // row in [0, N*H)
  const int n = r >> 8;      // H = 256
  const int h = r & (H_ - 1);
  const int tb = tile * TILE;
  const int w0l = tl << 2;
  const int w0g = tb + w0l;

  const size_t row_base = ((size_t)n * C_ * H_ + (size_t)h) * W_;

  // Staging columns (clamped at image edges; clamped values only reach
  // disparity outputs the epilogue zeroes).
  const int gx = tb + tid;
  int gy0 = tb - 12 + tid;
  gy0 = gy0 < 0 ? 0 : (gy0 > W_ - 1 ? W_ - 1 : gy0);
  int gy1 = tb - 12 + 256 + tid;
  gy1 = gy1 < 0 ? 0 : (gy1 > W_ - 1 ? W_ - 1 : gy1);
  const bool extra = tid < (YST - 256);  // 32 threads stage the y tail

  const float* px = x + row_base + gx;
  const float* py0 = y + row_base + gy0;
  const float* py1 = y + row_base + gy1;
  float* op = out + (size_t)n * DISP_ * CH + (size_t)h * W_ + w0g;

  if (g == 0)
    body<0>(px, py0, py1, extra, op, lds, tid, w0l, w0g);
  else if (g == 1)
    body<1>(px, py0, py1, extra, op, lds, tid, w0l, w0g);
  else if (g == 2)
    body<2>(px, py0, py1, extra, op, lds, tid, w0l, w0g);
  else
    body<3>(px, py0, py1, extra, op, lds, tid, w0l, w0g);
}

extern "C" void kernel_launch(void* const* d_in, const int* in_sizes, int n_in,
                              void* d_out, int out_size, void* d_ws, size_t ws_size,
                              hipStream_t stream) {
  const float* x = (const float*)d_in[0];
  const float* y = (const float*)d_in[1];
  float* out = (float*)d_out;
  dim3 grid(N_ * H_ * 2);  // 256-col tile per block
  dim3 block(256);
  hipLaunchKernelGGL(rescost_kernel, grid, block, 0, stream, x, y, out);
}